// Round 3
// baseline (462.385 us; speedup 1.0000x reference)
//
#include <hip/hip_runtime.h>
#include <hip/hip_bf16.h>

typedef __bf16 bf16_t;
typedef __attribute__((ext_vector_type(8))) __bf16 bf16x8;
typedef __attribute__((ext_vector_type(4))) __bf16 bf16x4;
typedef __attribute__((ext_vector_type(4))) float floatx4;

// B=8, N=4096, D=CV=128. fp32 in/out; bf16 MFMA compute, fp32 accumulate.
static constexpr int NSEQ = 4096;
static constexpr int DIM  = 128;
static constexpr int BATCH = 8;
static constexpr size_t NELEM = (size_t)BATCH * NSEQ * DIM;
static constexpr size_t WS_NEED = 2 * NELEM * sizeof(bf16_t);   // Kb + Vt = 16 MiB

// 1/sqrt(128) * log2(e); folded into Q at load so inner loop is bare exp2.
static constexpr float SCALE_LOG2E = 0.08838834764831845f * 1.4426950408889634f;

// ---------------- conversion kernels ----------------

__global__ __launch_bounds__(256)
void cvt_k_kernel(const float* __restrict__ K, bf16_t* __restrict__ Kb) {
  const size_t n4 = NELEM / 4;
  for (size_t i = (size_t)blockIdx.x * blockDim.x + threadIdx.x; i < n4;
       i += (size_t)gridDim.x * blockDim.x) {
    float4 k = ((const float4*)K)[i];
    bf16x4 kv = {(__bf16)k.x, (__bf16)k.y, (__bf16)k.z, (__bf16)k.w};
    ((bf16x4*)Kb)[i] = kv;
  }
}

// V [B][4096][128] fp32 -> Vt [B][128][4096] bf16
__global__ __launch_bounds__(256)
void cvt_vt_kernel(const float* __restrict__ V, bf16_t* __restrict__ Vt) {
  __shared__ bf16_t tile[32][33];
  const int bid = blockIdx.x;              // 8*128*4 = 4096 blocks
  const int b   = bid >> 9;
  const int rem = bid & 511;
  const int kt  = rem >> 2;
  const int nt  = rem & 3;
  const int tx  = threadIdx.x & 31;
  const int ty  = threadIdx.x >> 5;
  const float* Vb = V + ((size_t)b * NSEQ + kt * 32) * DIM + nt * 32;
  #pragma unroll
  for (int i = 0; i < 4; ++i) {
    int k = ty + i * 8;
    tile[k][tx] = (__bf16)Vb[(size_t)k * DIM + tx];
  }
  __syncthreads();
  bf16_t* Vtb = Vt + ((size_t)b * DIM + nt * 32) * NSEQ + kt * 32;
  #pragma unroll
  for (int i = 0; i < 4; ++i) {
    int n = ty + i * 8;
    Vtb[(size_t)n * NSEQ + tx] = tile[tx][n];
  }
}

// ---------------- flash attention, no-max online softmax ----------------

__device__ __forceinline__ bf16x8 ld8_f32s(const float* p, float s) {
  float4 a = *(const float4*)p;
  float4 b = *(const float4*)(p + 4);
  bf16x8 r = {(__bf16)(a.x * s), (__bf16)(a.y * s), (__bf16)(a.z * s), (__bf16)(a.w * s),
              (__bf16)(b.x * s), (__bf16)(b.y * s), (__bf16)(b.z * s), (__bf16)(b.w * s)};
  return r;
}

// One 64-key tile. MASK only for the single diagonal tail tile.
template <bool FAST, bool MASK>
__device__ __forceinline__ void attn_tile(
    int kb, int b, int l16, int quad, int q_base,
    const bf16x8 (&qf)[4], const void* __restrict__ Kp, const void* __restrict__ Vp,
    bf16_t* __restrict__ pl, floatx4 (&acc)[8], float (&lsum)[4]) {
  // ---- S = Q K^T : 4 chunks of 16 keys, 4 independent MFMA chains ----
  floatx4 s[4];
  #pragma unroll
  for (int c4 = 0; c4 < 4; ++c4) s[c4] = (floatx4){0.f, 0.f, 0.f, 0.f};

  if constexpr (FAST) {
    const bf16_t* kbase = (const bf16_t*)Kp + ((size_t)b * NSEQ + kb + l16) * DIM + quad * 8;
    #pragma unroll
    for (int c4 = 0; c4 < 4; ++c4) {
      #pragma unroll
      for (int d = 0; d < 4; ++d) {
        bf16x8 kf = *(const bf16x8*)(kbase + (size_t)c4 * 16 * DIM + 32 * d);
        s[c4] = __builtin_amdgcn_mfma_f32_16x16x32_bf16(qf[d], kf, s[c4], 0, 0, 0);
      }
    }
  } else {
    const float* kbase = (const float*)Kp + ((size_t)b * NSEQ + kb + l16) * DIM + quad * 8;
    #pragma unroll
    for (int c4 = 0; c4 < 4; ++c4) {
      #pragma unroll
      for (int d = 0; d < 4; ++d) {
        bf16x8 kf = ld8_f32s(kbase + (size_t)c4 * 16 * DIM + 32 * d, 1.0f);
        s[c4] = __builtin_amdgcn_mfma_f32_16x16x32_bf16(qf[d], kf, s[c4], 0, 0, 0);
      }
    }
  }

  // ---- p = exp2(s) (scale pre-folded into Q); stage P for C->A transpose ----
  #pragma unroll
  for (int c4 = 0; c4 < 4; ++c4) {
    #pragma unroll
    for (int r = 0; r < 4; ++r) {
      float v = s[c4][r];
      if constexpr (MASK) {
        const int qi = q_base + quad * 4 + r;
        v = (kb + c4 * 16 + l16 <= qi) ? v : -3.0e38f;   // exp2 -> exact 0
      }
      const float p = __builtin_amdgcn_exp2f(v);
      lsum[r] += p;                                       // deferred l-reduction
      pl[(quad * 4 + r) * 72 + c4 * 16 + l16] = (__bf16)p;
    }
  }

  // wave-internal LDS round trip (per-wave buffer, DS pipe is in-order)
  asm volatile("s_waitcnt lgkmcnt(0)" ::: "memory");
  const bf16x8 pfA = *(const bf16x8*)(pl + l16 * 72 + quad * 8);
  const bf16x8 pfB = *(const bf16x8*)(pl + l16 * 72 + 32 + quad * 8);

  // ---- O += P(16x64) * V(64x128) ----
  if constexpr (FAST) {
    const bf16_t* vt = (const bf16_t*)Vp + (size_t)b * DIM * NSEQ + kb + quad * 8;
    #pragma unroll
    for (int c = 0; c < 8; ++c) {
      const bf16_t* vr = vt + (size_t)(c * 16 + l16) * NSEQ;
      bf16x8 vfA = *(const bf16x8*)(vr);
      bf16x8 vfB = *(const bf16x8*)(vr + 32);
      acc[c] = __builtin_amdgcn_mfma_f32_16x16x32_bf16(pfA, vfA, acc[c], 0, 0, 0);
      acc[c] = __builtin_amdgcn_mfma_f32_16x16x32_bf16(pfB, vfB, acc[c], 0, 0, 0);
    }
  } else {
    const float* vb = (const float*)Vp + ((size_t)b * NSEQ + kb) * DIM;
    #pragma unroll
    for (int c = 0; c < 8; ++c) {
      bf16x8 vfA, vfB;
      #pragma unroll
      for (int j = 0; j < 8; ++j) {
        vfA[j] = (__bf16)vb[(size_t)(quad * 8 + j) * DIM + c * 16 + l16];
        vfB[j] = (__bf16)vb[(size_t)(32 + quad * 8 + j) * DIM + c * 16 + l16];
      }
      acc[c] = __builtin_amdgcn_mfma_f32_16x16x32_bf16(pfA, vfA, acc[c], 0, 0, 0);
      acc[c] = __builtin_amdgcn_mfma_f32_16x16x32_bf16(pfB, vfB, acc[c], 0, 0, 0);
    }
  }
}

template <bool FAST>
__global__ __launch_bounds__(256)
void causal_attn_kernel(const float* __restrict__ Qf, const void* __restrict__ Kp,
                        const void* __restrict__ Vp, float* __restrict__ Out) {
  // Per-wave P scratch: 16 rows x 64 keys, stride 72 bf16 (144 B, 16B-aligned)
  __shared__ bf16_t p_lds[4][16 * 72];

  const int bid  = blockIdx.x;
  const int t    = bid >> 3;
  const int b    = bid & 7;
  const int tid  = (int)threadIdx.x;
  const int wave = tid >> 6;
  const int lane = tid & 63;
  const int l16  = lane & 15;
  const int quad = lane >> 4;

  // waves 0,1 -> qtile t ; waves 2,3 -> qtile 127-t : balanced blocks
  const int qtile  = (wave < 2) ? t : (127 - t);
  const int q_base = qtile * 32 + (wave & 1) * 16;

  // Q: fp32 read, softmax scale folded in, cvt to bf16 A-fragments
  bf16x8 qf[4];
  {
    const float* qrow = Qf + ((size_t)b * NSEQ + q_base + l16) * DIM + quad * 8;
    #pragma unroll
    for (int d = 0; d < 4; ++d) qf[d] = ld8_f32s(qrow + 32 * d, SCALE_LOG2E);
  }

  floatx4 acc[8];
  #pragma unroll
  for (int c = 0; c < 8; ++c) acc[c] = (floatx4){0.f, 0.f, 0.f, 0.f};
  float lsum[4] = {0.f, 0.f, 0.f, 0.f};

  bf16_t* pl = p_lds[wave];
  const int nfull = q_base >> 6;   // 64-key tiles fully below the diagonal

  for (int kt = 0; kt < nfull; ++kt)
    attn_tile<FAST, false>(kt * 64, b, l16, quad, q_base, qf, Kp, Vp, pl, acc, lsum);
  attn_tile<FAST, true>(nfull * 64, b, l16, quad, q_base, qf, Kp, Vp, pl, acc, lsum);

  // ---- epilogue: one l-reduction, normalize, store fp32 ----
  float inv_l[4];
  #pragma unroll
  for (int r = 0; r < 4; ++r) {
    float s = lsum[r];
    #pragma unroll
    for (int off = 1; off < 16; off <<= 1) s += __shfl_xor(s, off, 64);
    inv_l[r] = 1.0f / s;
  }

  float* orow = Out + ((size_t)b * NSEQ + q_base + quad * 4) * DIM + l16;
  #pragma unroll
  for (int c = 0; c < 8; ++c) {
    #pragma unroll
    for (int r = 0; r < 4; ++r)
      orow[(size_t)r * DIM + c * 16] = acc[c][r] * inv_l[r];
  }
}

extern "C" void kernel_launch(void* const* d_in, const int* in_sizes, int n_in,
                              void* d_out, int out_size, void* d_ws, size_t ws_size,
                              hipStream_t stream) {
  const float* Q = (const float*)d_in[0];
  const float* K = (const float*)d_in[1];
  const float* V = (const float*)d_in[2];
  float* Out = (float*)d_out;
  (void)in_sizes; (void)n_in; (void)out_size;

  dim3 block(256);
  if (ws_size >= WS_NEED) {
    bf16_t* Kb = (bf16_t*)d_ws;
    bf16_t* Vt = Kb + NELEM;
    cvt_k_kernel<<<dim3(1024), block, 0, stream>>>(K, Kb);
    cvt_vt_kernel<<<dim3(4096), block, 0, stream>>>(V, Vt);
    causal_attn_kernel<true><<<dim3(512), block, 0, stream>>>(Q, Kb, Vt, Out);
  } else {
    causal_attn_kernel<false><<<dim3(512), block, 0, stream>>>(Q, K, V, Out);
  }
}

// Round 4
// 189.313 us; speedup vs baseline: 2.4424x; 2.4424x over previous
//
#include <hip/hip_runtime.h>
#include <hip/hip_bf16.h>

typedef __bf16 bf16_t;
typedef __attribute__((ext_vector_type(8))) __bf16 bf16x8;
typedef __attribute__((ext_vector_type(4))) __bf16 bf16x4;
typedef __attribute__((ext_vector_type(4))) float floatx4;

// B=8, N=4096, D=CV=128. fp32 in/out; bf16 MFMA compute, fp32 accumulate.
static constexpr int NSEQ = 4096;
static constexpr int DIM  = 128;
static constexpr int BATCH = 8;
static constexpr size_t NELEM = (size_t)BATCH * NSEQ * DIM;
static constexpr size_t WS_NEED = 2 * NELEM * sizeof(bf16_t);   // Kb + Vt = 16 MiB

// 1/sqrt(128) * log2(e); folded into Q so the inner loop is bare exp2.
static constexpr float SCALE_LOG2E = 0.08838834764831845f * 1.4426950408889634f;

// async global->LDS, 16B per lane; LDS dest = wave-uniform base + lane*16
__device__ __forceinline__ void gld16(bf16_t* l, const bf16_t* g) {
  __builtin_amdgcn_global_load_lds(
      (const __attribute__((address_space(1))) unsigned int*)g,
      (__attribute__((address_space(3))) unsigned int*)l, 16, 0, 0);
}

__device__ __forceinline__ bf16x8 ld8_f32s(const float* p, float s) {
  float4 a = *(const float4*)p;
  float4 b = *(const float4*)(p + 4);
  bf16x8 r = {(__bf16)(a.x * s), (__bf16)(a.y * s), (__bf16)(a.z * s), (__bf16)(a.w * s),
              (__bf16)(b.x * s), (__bf16)(b.y * s), (__bf16)(b.z * s), (__bf16)(b.w * s)};
  return r;
}

// ---------------- prep: K fp32->bf16, V fp32 -> Vt bf16 [B][dim][key] ----------------

__global__ __launch_bounds__(256)
void prep_kernel(const float* __restrict__ K, const float* __restrict__ V,
                 bf16_t* __restrict__ Kb, bf16_t* __restrict__ Vt) {
  __shared__ bf16_t tile[32][33];
  const int bid = blockIdx.x;
  if (bid < 1024) {                       // K convert
    const size_t n4 = NELEM / 4;
    for (size_t i = (size_t)bid * 256 + threadIdx.x; i < n4; i += 1024 * 256) {
      float4 k = ((const float4*)K)[i];
      bf16x4 kv = {(__bf16)k.x, (__bf16)k.y, (__bf16)k.z, (__bf16)k.w};
      ((bf16x4*)Kb)[i] = kv;
    }
  } else {                                // V transpose+convert (32x32 LDS tiles)
    const int id = bid - 1024;            // 0..4095
    const int b = id >> 9, rem = id & 511, kt = rem >> 2, nt = rem & 3;
    const int tx = threadIdx.x & 31, ty = threadIdx.x >> 5;
    const float* Vb = V + ((size_t)b * NSEQ + kt * 32) * DIM + nt * 32;
    #pragma unroll
    for (int i = 0; i < 4; ++i) {
      int k = ty + i * 8;
      tile[k][tx] = (__bf16)Vb[(size_t)k * DIM + tx];
    }
    __syncthreads();
    bf16_t* Vtb = Vt + ((size_t)b * DIM + nt * 32) * NSEQ + kt * 32;
    #pragma unroll
    for (int i = 0; i < 4; ++i) {
      int n = ty + i * 8;
      Vtb[(size_t)n * NSEQ + tx] = tile[tx][n];
    }
  }
}

// ---------------- attention: 64-q block, LDS-staged 64-key tiles ----------------

template <bool MASK>
__device__ __forceinline__ void tile_compute(
    const bf16_t* __restrict__ kbuf, const bf16_t* __restrict__ vbuf,
    bf16_t* __restrict__ pl, const bf16x8 (&qf)[4],
    int l16, int quad, int wq, floatx4 (&acc)[8], float (&lsum)[4]) {
  // ---- S = Q K^T (16q x 64k), LDS K reads XOR-swizzled ----
  floatx4 s[4];
  #pragma unroll
  for (int c4 = 0; c4 < 4; ++c4) s[c4] = (floatx4){0.f, 0.f, 0.f, 0.f};
  #pragma unroll
  for (int c4 = 0; c4 < 4; ++c4) {
    const bf16_t* krow = kbuf + (c4 * 16 + l16) * DIM;
    #pragma unroll
    for (int d = 0; d < 4; ++d) {
      bf16x8 kf = *(const bf16x8*)(krow + (((4 * d + quad) ^ l16) * 8));
      s[c4] = __builtin_amdgcn_mfma_f32_16x16x32_bf16(qf[d], kf, s[c4], 0, 0, 0);
    }
  }
  // ---- p = exp2(s); stage P (C-layout -> A-layout via per-wave LDS) ----
  #pragma unroll
  for (int c4 = 0; c4 < 4; ++c4) {
    #pragma unroll
    for (int r = 0; r < 4; ++r) {
      float v = s[c4][r];
      if constexpr (MASK)
        v = (c4 * 16 + l16 <= wq + quad * 4 + r) ? v : -3.0e38f;  // exp2 -> 0
      float p = __builtin_amdgcn_exp2f(v);
      lsum[r] += p;                       // deferred l-reduction
      pl[(quad * 4 + r) * 72 + c4 * 16 + l16] = (__bf16)p;
    }
  }
  asm volatile("s_waitcnt lgkmcnt(0)" ::: "memory");  // drain P writes (in-wave)
  bf16x8 pfA = *(const bf16x8*)(pl + l16 * 72 + quad * 8);
  bf16x8 pfB = *(const bf16x8*)(pl + l16 * 72 + 32 + quad * 8);
  // ---- O += P(16x64) * V(64x128), LDS V reads XOR-swizzled ----
  #pragma unroll
  for (int c = 0; c < 8; ++c) {
    const bf16_t* vrow = vbuf + (c * 16 + l16) * 64;
    bf16x8 vfA = *(const bf16x8*)(vrow + ((quad ^ (l16 & 7)) * 8));
    bf16x8 vfB = *(const bf16x8*)(vrow + (((quad + 4) ^ (l16 & 7)) * 8));
    acc[c] = __builtin_amdgcn_mfma_f32_16x16x32_bf16(pfA, vfA, acc[c], 0, 0, 0);
    acc[c] = __builtin_amdgcn_mfma_f32_16x16x32_bf16(pfB, vfB, acc[c], 0, 0, 0);
  }
}

__global__ __launch_bounds__(256)
void causal_attn_kernel(const float* __restrict__ Qf, const bf16_t* __restrict__ Kb,
                        const bf16_t* __restrict__ Vt, float* __restrict__ Out) {
  // K tile [key 64][dim 128] (16B chunks swizzled by key&15)  : 16 KB
  // V tile [dim 128][key 64] (16B chunks swizzled by dim&7)   : 16 KB
  // P transpose scratch per wave, stride 72 bf16 (144 B)      :  9 KB
  __shared__ __align__(16) bf16_t Kbuf[64 * DIM];
  __shared__ __align__(16) bf16_t Vbuf[DIM * 64];
  __shared__ __align__(16) bf16_t Pbuf[4][16 * 72];

  // balance: first 256 blocks get long qtiles (63..32), next 256 short (0..31);
  // linear dispatch pairs them per CU -> ~65 tile-steps per CU.
  const int half = blockIdx.x >> 8;
  const int idx  = blockIdx.x & 255;
  const int b    = idx & 7;
  const int q32  = idx >> 3;              // 0..31
  const int qt64 = half ? q32 : 63 - q32;

  const int tid  = (int)threadIdx.x;
  const int wave = tid >> 6;
  const int lane = tid & 63;
  const int l16  = lane & 15;
  const int quad = lane >> 4;
  const int wq   = wave * 16;             // wave's query offset within block

  // Q fragments: fp32 read, scale folded, A-layout A[m=l16][k=quad*8+j]
  bf16x8 qf[4];
  {
    const float* qrow = Qf + ((size_t)b * NSEQ + qt64 * 64 + wq + l16) * DIM + quad * 8;
    #pragma unroll
    for (int d = 0; d < 4; ++d) qf[d] = ld8_f32s(qrow + 32 * d, SCALE_LOG2E);
  }

  // staging addresses (wave w stages K rows 16w..16w+15, V dims 32w..32w+31)
  const bf16_t* kg0 = Kb + ((size_t)b * NSEQ + 16 * wave) * DIM;
  const bf16_t* vg0 = Vt + ((size_t)b * DIM + 32 * wave) * NSEQ;
  int koff[4], voff[4];
  #pragma unroll
  for (int i = 0; i < 4; ++i) {
    const int krow = 4 * i + (lane >> 4);                    // 0..15
    koff[i] = krow * DIM + (((lane & 15) ^ (krow & 15)) * 8);
    const int vrow = 8 * i + (lane >> 3);                    // 0..31
    voff[i] = vrow * NSEQ + (((lane & 7) ^ ((lane >> 3) & 7)) * 8);
  }
  bf16_t* kl = Kbuf + 16 * wave * DIM;
  bf16_t* vl = Vbuf + 32 * wave * 64;
  bf16_t* pl = Pbuf[wave];

  floatx4 acc[8];
  #pragma unroll
  for (int c = 0; c < 8; ++c) acc[c] = (floatx4){0.f, 0.f, 0.f, 0.f};
  float lsum[4] = {0.f, 0.f, 0.f, 0.f};

  const int nk = qt64 + 1;                // 64-key tiles; only last is masked
  for (int kt = 0; kt < nk - 1; ++kt) {
    const int kb = kt * 64;
    #pragma unroll
    for (int i = 0; i < 4; ++i) gld16(kl + i * 512, kg0 + (size_t)kb * DIM + koff[i]);
    #pragma unroll
    for (int i = 0; i < 4; ++i) gld16(vl + i * 512, vg0 + kb + voff[i]);
    __syncthreads();                      // staged data visible to all waves
    tile_compute<false>(Kbuf, Vbuf, pl, qf, l16, quad, wq, acc, lsum);
    __syncthreads();                      // all reads done before re-staging
  }
  {
    const int kb = (nk - 1) * 64;
    #pragma unroll
    for (int i = 0; i < 4; ++i) gld16(kl + i * 512, kg0 + (size_t)kb * DIM + koff[i]);
    #pragma unroll
    for (int i = 0; i < 4; ++i) gld16(vl + i * 512, vg0 + kb + voff[i]);
    __syncthreads();
    tile_compute<true>(Kbuf, Vbuf, pl, qf, l16, quad, wq, acc, lsum);
  }

  // ---- epilogue: single l-reduction, normalize, fp32 store ----
  float inv_l[4];
  #pragma unroll
  for (int r = 0; r < 4; ++r) {
    float s = lsum[r];
    #pragma unroll
    for (int off = 1; off < 16; off <<= 1) s += __shfl_xor(s, off, 64);
    inv_l[r] = 1.0f / s;
  }
  float* orow = Out + ((size_t)b * NSEQ + qt64 * 64 + wq + quad * 4) * DIM + l16;
  #pragma unroll
  for (int c = 0; c < 8; ++c) {
    #pragma unroll
    for (int r = 0; r < 4; ++r)
      orow[(size_t)r * DIM + c * 16] = acc[c][r] * inv_l[r];
  }
}

// ---------------- fallback (no workspace): round-3 structure, fp32 direct ----------------

__global__ __launch_bounds__(256)
void causal_attn_fb(const float* __restrict__ Qf, const float* __restrict__ Kf,
                    const float* __restrict__ Vf, float* __restrict__ Out) {
  __shared__ bf16_t p_lds[4][16 * 72];
  const int bid = blockIdx.x, t = bid >> 3, b = bid & 7;
  const int tid = (int)threadIdx.x, wave = tid >> 6, lane = tid & 63;
  const int l16 = lane & 15, quad = lane >> 4;
  const int qtile = (wave < 2) ? t : (127 - t);
  const int q_base = qtile * 32 + (wave & 1) * 16;

  bf16x8 qf[4];
  const float* qrow = Qf + ((size_t)b * NSEQ + q_base + l16) * DIM + quad * 8;
  #pragma unroll
  for (int d = 0; d < 4; ++d) qf[d] = ld8_f32s(qrow + 32 * d, SCALE_LOG2E);

  floatx4 acc[8];
  #pragma unroll
  for (int c = 0; c < 8; ++c) acc[c] = (floatx4){0.f, 0.f, 0.f, 0.f};
  float lsum[4] = {0.f, 0.f, 0.f, 0.f};
  bf16_t* pl = p_lds[wave];
  const int ntiles = (q_base + 16 + 63) >> 6;

  for (int kt = 0; kt < ntiles; ++kt) {
    const int kb = kt * 64;
    floatx4 s[4];
    #pragma unroll
    for (int c4 = 0; c4 < 4; ++c4) s[c4] = (floatx4){0.f, 0.f, 0.f, 0.f};
    const float* kbase = Kf + ((size_t)b * NSEQ + kb + l16) * DIM + quad * 8;
    #pragma unroll
    for (int c4 = 0; c4 < 4; ++c4) {
      #pragma unroll
      for (int d = 0; d < 4; ++d) {
        bf16x8 kf = ld8_f32s(kbase + (size_t)c4 * 16 * DIM + 32 * d, 1.0f);
        s[c4] = __builtin_amdgcn_mfma_f32_16x16x32_bf16(qf[d], kf, s[c4], 0, 0, 0);
      }
    }
    #pragma unroll
    for (int c4 = 0; c4 < 4; ++c4) {
      #pragma unroll
      for (int r = 0; r < 4; ++r) {
        float v = s[c4][r];
        const int qi = q_base + quad * 4 + r;
        v = (kb + c4 * 16 + l16 <= qi) ? v : -3.0e38f;
        float p = __builtin_amdgcn_exp2f(v);
        lsum[r] += p;
        pl[(quad * 4 + r) * 72 + c4 * 16 + l16] = (__bf16)p;
      }
    }
    asm volatile("s_waitcnt lgkmcnt(0)" ::: "memory");
    bf16x8 pfA = *(const bf16x8*)(pl + l16 * 72 + quad * 8);
    bf16x8 pfB = *(const bf16x8*)(pl + l16 * 72 + 32 + quad * 8);
    const float* vb = Vf + ((size_t)b * NSEQ + kb) * DIM;
    #pragma unroll
    for (int c = 0; c < 8; ++c) {
      bf16x8 vfA, vfB;
      #pragma unroll
      for (int j = 0; j < 8; ++j) {
        vfA[j] = (__bf16)vb[(size_t)(quad * 8 + j) * DIM + c * 16 + l16];
        vfB[j] = (__bf16)vb[(size_t)(32 + quad * 8 + j) * DIM + c * 16 + l16];
      }
      acc[c] = __builtin_amdgcn_mfma_f32_16x16x32_bf16(pfA, vfA, acc[c], 0, 0, 0);
      acc[c] = __builtin_amdgcn_mfma_f32_16x16x32_bf16(pfB, vfB, acc[c], 0, 0, 0);
    }
  }
  float inv_l[4];
  #pragma unroll
  for (int r = 0; r < 4; ++r) {
    float s = lsum[r];
    #pragma unroll
    for (int off = 1; off < 16; off <<= 1) s += __shfl_xor(s, off, 64);
    inv_l[r] = 1.0f / s;
  }
  float* orow = Out + ((size_t)b * NSEQ + q_base + quad * 4) * DIM + l16;
  #pragma unroll
  for (int c = 0; c < 8; ++c) {
    #pragma unroll
    for (int r = 0; r < 4; ++r)
      orow[(size_t)r * DIM + c * 16] = acc[c][r] * inv_l[r];
  }
}

extern "C" void kernel_launch(void* const* d_in, const int* in_sizes, int n_in,
                              void* d_out, int out_size, void* d_ws, size_t ws_size,
                              hipStream_t stream) {
  const float* Q = (const float*)d_in[0];
  const float* K = (const float*)d_in[1];
  const float* V = (const float*)d_in[2];
  float* Out = (float*)d_out;
  (void)in_sizes; (void)n_in; (void)out_size;

  dim3 block(256);
  if (ws_size >= WS_NEED) {
    bf16_t* Kb = (bf16_t*)d_ws;
    bf16_t* Vt = Kb + NELEM;
    prep_kernel<<<dim3(5120), block, 0, stream>>>(K, V, Kb, Vt);
    causal_attn_kernel<<<dim3(512), block, 0, stream>>>(Q, Kb, Vt, Out);
  } else {
    causal_attn_fb<<<dim3(512), block, 0, stream>>>(Q, K, V, Out);
  }
}